// Round 3
// baseline (128.046 us; speedup 1.0000x reference)
//
#include <hip/hip_runtime.h>

#define BATCH 16384
#define DIM   512
#define UNITS 1024
// GAMMA = 0.5 folded: out = exp(cross - 0.5*xsq - 0.5*musq)

typedef float v16f __attribute__((ext_vector_type(16)));
#define MFMA_F8(a, b, c) __builtin_amdgcn_mfma_f32_32x32x16_fp8_fp8((a), (b), (c), 0, 0, 0)

static __device__ __forceinline__ long cvt8(const float4 f0, const float4 f1) {
    int lo = __builtin_amdgcn_cvt_pk_fp8_f32(f0.x, f0.y, 0, false);
    lo     = __builtin_amdgcn_cvt_pk_fp8_f32(f0.z, f0.w, lo, true);
    int hi = __builtin_amdgcn_cvt_pk_fp8_f32(f1.x, f1.y, 0, false);
    hi     = __builtin_amdgcn_cvt_pk_fp8_f32(f1.z, f1.w, hi, true);
    return (long)(unsigned)lo | ((long)hi << 32);
}
static __device__ __forceinline__ float dot8(const float4 f0, const float4 f1) {
    return f0.x * f0.x + f0.y * f0.y + f0.z * f0.z + f0.w * f0.w
         + f1.x * f1.x + f1.y * f1.y + f1.z * f1.z + f1.w * f1.w;
}

// Fused RBF, 512 blocks x 512 threads (8 waves), 2 blocks/CU, ONE grid round.
// Block tile 256M x 128N; wave w owns m-rows [m0+w*32, +32) x ALL 128 n-cols
// (4 accumulators). Grid: xcd=b&7, j=b>>3, mt=xcd*8+(j&7), nt=j>>3 -> the 8
// blocks sharing an m-tile sit on one XCD; co-resident pair (b, b+256) shares
// the SAME m-tile (L1/L2-local A).
//
// Key change vs prev round: NO barriers in the K-loop. A fragments are loaded
// straight from global per-wave (lane l = row m0+w*32+(l&31), k-half l>>5:
// two float4s), converted fp32->fp8 in registers (cvt_pk), xsq accumulated
// per-lane. B (64 KB fp8 fragment order) staged in LDS once; ds_read_b64 is
// lane-linear (conflict-free). Waves free-run -> latency hidden by drift+TLP.
__global__ __launch_bounds__(512, 4)
void rbf_fused_kernel(const float* __restrict__ in, const float* __restrict__ mu,
                      float* __restrict__ out) {
    __shared__ __attribute__((aligned(16))) unsigned char smem[67072];
    unsigned char* Bs = smem;                    // [4 ng][32 kw][64 l][8] fp8
    float* musq_red = (float*)(smem + 65536);    // [128][2]
    float* musq_l   = (float*)(smem + 66560);    // [128]

    const int t  = threadIdx.x;
    const int l  = t & 63;
    const int w  = t >> 6;          // wave 0..7 = m-group
    const int ln = l & 31;
    const int h  = l >> 5;

    const int b   = blockIdx.x;     // 0..511
    const int xcd = b & 7;
    const int j   = b >> 3;         // 0..63
    const int m0  = (xcd * 8 + (j & 7)) * 256;
    const int n0  = (j >> 3) * 128;

    // Per-wave A row pointer: lane l covers row m0+w*32+ln, k-half h.
    const float4* ap = (const float4*)(in + (size_t)(m0 + w * 32 + ln) * DIM + h * 8);
    // Prefetch chunks 0,1 (latency hides under phase B).
    float4 p0a = ap[0], p0b = ap[1];
    float4 p1a = ap[4], p1b = ap[5];

    // ---- Phase B: mu -> fp8 fragments in LDS + musq ----
    {
        const int ng = w >> 1;              // 0..3: 32-col group
        const int kq = w & 1;               // k-half (16 kw = 256 k)
        const float* msrc = mu + (size_t)(kq * 256 + h * 8) * UNITS + n0 + ng * 32 + ln;
        unsigned char* bdst = Bs + (size_t)(((ng * 32 + kq * 16) * 64) + l) * 8;
        float s = 0.f;
#pragma unroll 4
        for (int kk = 0; kk < 16; kk++) {
            float v[8];
#pragma unroll
            for (int jj = 0; jj < 8; jj++) v[jj] = msrc[(size_t)(kk * 16 + jj) * UNITS];
#pragma unroll
            for (int jj = 0; jj < 8; jj++) s += v[jj] * v[jj];
            *(long*)(bdst + kk * 512) =
                cvt8(make_float4(v[0], v[1], v[2], v[3]),
                     make_float4(v[4], v[5], v[6], v[7]));
        }
        s += __shfl_xor(s, 32, 64);         // combine the two k-octets (h)
        if (h == 0) musq_red[(ng * 32 + ln) * 2 + kq] = s;
    }
    __syncthreads();
    if (t < 128) musq_l[t] = -0.5f * (musq_red[t * 2] + musq_red[t * 2 + 1]);
    __syncthreads();                         // last barrier in the kernel

    // ---- Barrier-free K-loop: 32 chunks x (1 A cvt + 4 ds_read + 4 MFMA) ----
    const long* BsL = (const long*)Bs;
    v16f acc0 = (v16f)0.f, acc1 = (v16f)0.f, acc2 = (v16f)0.f, acc3 = (v16f)0.f;
    float sA = 0.f;

#pragma unroll 2
    for (int i = 0; i < 32; i++) {
        const float4 f0 = (i & 1) ? p1a : p0a;
        const float4 f1 = (i & 1) ? p1b : p0b;
        sA += dot8(f0, f1);
        const long a = cvt8(f0, f1);
        if (i < 30) {                        // refill just-freed buffer (depth 2)
            if (i & 1) { p1a = ap[(i + 2) * 4]; p1b = ap[(i + 2) * 4 + 1]; }
            else       { p0a = ap[(i + 2) * 4]; p0b = ap[(i + 2) * 4 + 1]; }
        }
        const int bo = i * 64 + l;
        const long b0 = BsL[bo];
        const long b1 = BsL[bo + 2048];
        const long b2 = BsL[bo + 4096];
        const long b3 = BsL[bo + 6144];
        acc0 = MFMA_F8(a, b0, acc0);
        acc1 = MFMA_F8(a, b1, acc1);
        acc2 = MFMA_F8(a, b2, acc2);
        acc3 = MFMA_F8(a, b3, acc3);
    }

    // ---- xsq entirely in registers ----
    sA += __shfl_xor(sA, 32, 64);            // lane ln holds row w*32+ln sum
    const float xv = -0.5f * sA;

    const float mb0 = musq_l[ln];
    const float mb1 = musq_l[32 + ln];
    const float mb2 = musq_l[64 + ln];
    const float mb3 = musq_l[96 + ln];

    // ---- Epilogue: C/D layout col=l&31, row=(r&3)+8*(r>>2)+4*h ----
    const size_t mrow = m0 + w * 32;
    float* obase = out + n0 + ln;
#pragma unroll
    for (int r = 0; r < 16; r++) {
        const int rl = (r & 3) + 8 * (r >> 2) + 4 * h;
        const float xb = __shfl(xv, rl, 64);  // row rl's -0.5*xsq
        float* orow = obase + (mrow + rl) * UNITS;
        __builtin_nontemporal_store(__expf(acc0[r] + xb + mb0), orow);
        __builtin_nontemporal_store(__expf(acc1[r] + xb + mb1), orow + 32);
        __builtin_nontemporal_store(__expf(acc2[r] + xb + mb2), orow + 64);
        __builtin_nontemporal_store(__expf(acc3[r] + xb + mb3), orow + 96);
    }
}

extern "C" void kernel_launch(void* const* d_in, const int* in_sizes, int n_in,
                              void* d_out, int out_size, void* d_ws, size_t ws_size,
                              hipStream_t stream) {
    const float* inputs = (const float*)d_in[0];   // [16384, 512] fp32
    const float* mu     = (const float*)d_in[1];   // [512, 1024] fp32
    float* out = (float*)d_out;                    // [16384, 1024] fp32
    (void)d_ws; (void)ws_size;                     // no workspace needed

    rbf_fused_kernel<<<512, 512, 0, stream>>>(inputs, mu, out);
}

// Round 4
// 110.942 us; speedup vs baseline: 1.1542x; 1.1542x over previous
//
#include <hip/hip_runtime.h>
#include <hip/hip_bf16.h>

#define BATCH 16384
#define DIM   512
#define UNITS 1024
// GAMMA = 0.5 folded into epilogue: out = exp(cross - 0.5*xsq - 0.5*musq)

typedef float v16f __attribute__((ext_vector_type(16)));

#define APITCH 516   // fp32 LDS pitch (floats) for prep-A transpose reads
#define BPITCH 33

#define MFMA_F8(a, b, c) __builtin_amdgcn_mfma_f32_32x32x16_fp8_fp8((a), (b), (c), 0, 0, 0)

__device__ __forceinline__ void async_copy16(const void* g, void* l) {
    __builtin_amdgcn_global_load_lds(
        (const __attribute__((address_space(1))) void*)g,
        (__attribute__((address_space(3))) void*)l,
        16 /*bytes*/, 0 /*offset*/, 0 /*aux*/);
}

// Fragment-order prep (fp8 e4m3), xsq/musq on ORIGINAL fp32 values.
// A8f: byte ((chunk*32 + kw)*64 + lane)*8 — lane l holds
//   A[chunk*32 + (l&31)][kw*16 + (l>>5)*8 + 0..7].
// B8f: byte ((ng*32 + kw)*64 + lane)*8 — lane l holds
//   B[kw*16 + (l>>5)*8 + 0..7][ng*32 + (l&31)].
// Blocks 0..31: B path (dispatched first; latency-bound). Blocks 32..543:
// A path, chunk c = ((b-32)&7)*64 + ((b-32)>>3) so that chunk c is converted
// on XCD floor(c/64) — the SAME XCD whose GEMM blocks read it (L2-local).
__global__ __launch_bounds__(256)
void prep_kernel(const float* __restrict__ in, const float* __restrict__ mu,
                 unsigned char* __restrict__ A8f, unsigned char* __restrict__ B8f,
                 float* __restrict__ xsq, float* __restrict__ musq) {
    __shared__ __attribute__((aligned(16))) char smem[512 * BPITCH * 4 + 1024];
    const int t  = threadIdx.x;
    const int l  = t & 63, w = t >> 6;
    const int ln = l & 31, h = l >> 5;

    if (blockIdx.x >= UNITS / 32) {
        // ---- A path: one block per 32-row chunk, XCD-matched to the GEMM ----
        float* lds = (float*)smem;                       // [32][APITCH]
        float* red = (float*)(smem + 32 * APITCH * 4);   // [32][8]
        const int bb = blockIdx.x - UNITS / 32;
        const int c  = (bb & 7) * 64 + (bb >> 3);        // chunk 0..511
        const float4* src = (const float4*)(in + (size_t)c * 32 * DIM);
        float4* l4 = (float4*)lds;
#pragma unroll
        for (int i = 0; i < 16; i++) {
            const int f = i * 256 + t;                   // float4 id 0..4095
            l4[(f >> 7) * (APITCH / 4) + (f & 127)] = src[f];
        }
        __syncthreads();
        float s = 0.f;
#pragma unroll
        for (int j = 0; j < 8; j++) {
            const int kw = w * 8 + j;
            const float* p = lds + ln * APITCH + kw * 16 + h * 8;
            float4 f0 = *(const float4*)p;
            float4 f1 = *(const float4*)(p + 4);
            s += f0.x * f0.x + f0.y * f0.y + f0.z * f0.z + f0.w * f0.w
               + f1.x * f1.x + f1.y * f1.y + f1.z * f1.z + f1.w * f1.w;
            int lo = __builtin_amdgcn_cvt_pk_fp8_f32(f0.x, f0.y, 0, false);
            lo     = __builtin_amdgcn_cvt_pk_fp8_f32(f0.z, f0.w, lo, true);
            int hi = __builtin_amdgcn_cvt_pk_fp8_f32(f1.x, f1.y, 0, false);
            hi     = __builtin_amdgcn_cvt_pk_fp8_f32(f1.z, f1.w, hi, true);
            *(int2*)(A8f + (((size_t)c * 32 + kw) * 64 + l) * 8) = make_int2(lo, hi);
        }
        red[ln * 8 + w * 2 + h] = s;
        __syncthreads();
        if (t < 32) {
            float a = 0.f;
#pragma unroll
            for (int i = 0; i < 8; i++) a += red[t * 8 + i];
            xsq[c * 32 + t] = a;
        }
    } else {
        // ---- B path: one block per 32-column group ----
        float* lds = (float*)smem;                       // [512][BPITCH]
        float* red = (float*)(smem + 512 * BPITCH * 4);  // [32][8]
        const int nb = blockIdx.x;
        const int n0 = nb * 32;
        const int col = t & 31, kg = t >> 5;
        float s = 0.f;
        for (int i = 0; i < 64; i++) {
            const int k = i * 8 + kg;
            float v = mu[(size_t)k * UNITS + n0 + col];
            s += v * v;
            lds[k * BPITCH + col] = v;
        }
        red[col * 8 + kg] = s;
        __syncthreads();
        if (t < 32) {
            float a = 0.f;
#pragma unroll
            for (int i = 0; i < 8; i++) a += red[t * 8 + i];
            musq[n0 + t] = a;
        }
#pragma unroll
        for (int j = 0; j < 8; j++) {
            const int kw = w * 8 + j;
            const float* p = lds + (kw * 16 + h * 8) * BPITCH + ln;
            float f[8];
#pragma unroll
            for (int i = 0; i < 8; i++) f[i] = p[i * BPITCH];
            int lo = __builtin_amdgcn_cvt_pk_fp8_f32(f[0], f[1], 0, false);
            lo     = __builtin_amdgcn_cvt_pk_fp8_f32(f[2], f[3], lo, true);
            int hi = __builtin_amdgcn_cvt_pk_fp8_f32(f[4], f[5], 0, false);
            hi     = __builtin_amdgcn_cvt_pk_fp8_f32(f[6], f[7], hi, true);
            *(int2*)(B8f + (((size_t)nb * 32 + kw) * 64 + l) * 8) = make_int2(lo, hi);
        }
    }
}

// RBF GEMM v2: 512 blocks x 512 threads (8 waves), 2 blocks/CU (64 KB LDS).
// Block tile 256M x 128N. Grid: xcd=b&7, j=b>>3, mt=xcd*8+(j&7), nt=j>>3;
// the 8 n-blocks of an m-tile sit on one XCD (L2-local A8f, matches prep
// placement); co-resident pair (b, b+256) shares the same m-tile.
// Wave tile 64M x 64N processed as TWO 32M x 64N passes: K-loop + store
// epilogue per pass, so pass-0 stores overlap pass-1 compute (and the two
// co-resident blocks drift freely -- no barriers after the B stage).
// Numerics identical to R0: same cvt path, same per-accumulator K order.
__global__ __launch_bounds__(512, 4)
void rbf_gemm_kernel(const unsigned char* __restrict__ A8f,
                     const unsigned char* __restrict__ B8f,
                     const float* __restrict__ xsq,
                     const float* __restrict__ musq,
                     float* __restrict__ out) {
    __shared__ __attribute__((aligned(16))) unsigned char Bs[65536]; // 64 KB

    const int t  = threadIdx.x;
    const int l  = t & 63;
    const int w  = t >> 6;          // wave 0..7
    const int ln = l & 31;
    const int h  = l >> 5;

    const int b   = blockIdx.x;     // 0..511
    const int xcd = b & 7;
    const int j   = b >> 3;         // 0..63
    const int m0  = (xcd * 8 + (j & 7)) * 256;
    const int n0  = (j >> 3) * 128;
    const int wm  = (w >> 1) * 64;  // wave row origin in tile (4 m-groups)
    const int wn  = (w & 1) * 64;   // wave col origin in tile (2 n-groups)

    // ---- Stage B-tile (contiguous 64 KB slice of B8f) into LDS ----
    const unsigned char* bsrc = B8f + (size_t)n0 * 512;  // nt*4 ng * 16384 B
#pragma unroll
    for (int i = 0; i < 8; i++) {
        const int c = i * 512 + t;                       // 16B chunk 0..4095
        async_copy16(bsrc + c * 16, Bs + c * 16);
    }
    __syncthreads();                                     // only barrier

    const long* BsL = (const long*)Bs;
    const long* Bp  = BsL + (size_t)(wn >> 5) * 2048 + l;

    // ---- Two M-passes: 32-row K-loop then immediate store epilogue ----
#pragma unroll
    for (int p = 0; p < 2; p++) {
        const int mbase = m0 + wm + p * 32;
        const long* Af = (const long*)A8f + (size_t)(mbase >> 5) * 2048 + l;

        v16f acc0 = (v16f)0.f, acc1 = (v16f)0.f;
#pragma unroll 4
        for (int kw = 0; kw < 32; kw++) {
            long a  = Af[kw * 64];
            long b0 = Bp[kw * 64];
            long b1 = Bp[2048 + kw * 64];
            acc0 = MFMA_F8(a, b0, acc0);
            acc1 = MFMA_F8(a, b1, acc1);
        }

        // Epilogue for rows [mbase, mbase+32). C/D layout: col = l&31,
        // row = (r&3) + 8*(r>>2) + 4*(l>>5).
        const float xv  = -0.5f * xsq[mbase + ln];       // lane ln: row mbase+ln
        const float mb0 = -0.5f * musq[n0 + wn + ln];
        const float mb1 = -0.5f * musq[n0 + wn + 32 + ln];
        float* obase = out + n0 + wn + ln;
#pragma unroll
        for (int r = 0; r < 16; r++) {
            const int rl = (r & 3) + 8 * (r >> 2) + 4 * h;
            const float xb = __shfl(xv, rl, 64);
            float* orow = obase + (size_t)(mbase + rl) * UNITS;
            __builtin_nontemporal_store(__expf(acc0[r] + xb + mb0), orow);
            __builtin_nontemporal_store(__expf(acc1[r] + xb + mb1), orow + 32);
        }
    }
}

extern "C" void kernel_launch(void* const* d_in, const int* in_sizes, int n_in,
                              void* d_out, int out_size, void* d_ws, size_t ws_size,
                              hipStream_t stream) {
    const float* inputs = (const float*)d_in[0];   // [16384, 512] fp32
    const float* mu     = (const float*)d_in[1];   // [512, 1024] fp32
    float* out = (float*)d_out;                    // [16384, 1024] fp32

    char* ws = (char*)d_ws;
    unsigned char* A8f = (unsigned char*)ws;                           // 8 MiB
    unsigned char* B8f = (unsigned char*)(ws + (size_t)BATCH * DIM);   // 512 KiB
    float* xsq  = (float*)(ws + (size_t)BATCH * DIM + (size_t)UNITS * DIM);
    float* musq = xsq + BATCH;

    prep_kernel<<<UNITS / 32 + BATCH / 32, 256, 0, stream>>>(
        inputs, mu, A8f, B8f, xsq, musq);
    rbf_gemm_kernel<<<512, 512, 0, stream>>>(A8f, B8f, xsq, musq, out);
}